// Round 2
// 248.743 us; speedup vs baseline: 1.0182x; 1.0182x over previous
//
#include <hip/hip_runtime.h>
#include <math.h>

#define B_   64
#define N_   197
#define C_   768
#define H_   12
#define D_   64
#define BN   12608      // B_*N_
#define BN_PAD 12672    // A-buffer allocated rows (99*128)
#define QKV_ELEMS 9682944   // B_*H_*N_*D_ = BN*C_
#define SCALE 0.125f    // D^-0.5
#define STRV 80         // Vt/Ps LDS row stride (ushorts): 160B, 16B-aligned

typedef unsigned short ushort_t;
using bf16x8  = __attribute__((ext_vector_type(8))) __bf16;
using floatx4 = __attribute__((ext_vector_type(4))) float;
using ushort8 = __attribute__((ext_vector_type(8))) unsigned short;

__device__ __forceinline__ ushort_t f2bf(float f) {
    union { float f; unsigned u; } v; v.f = f;
    unsigned r = v.u + 0x7FFF + ((v.u >> 16) & 1);   // RNE
    return (ushort_t)(r >> 16);
}

__device__ __forceinline__ void gload_lds16(const void* g, void* l) {
    __builtin_amdgcn_global_load_lds(
        (const __attribute__((address_space(1))) unsigned*)g,
        (__attribute__((address_space(3))) unsigned*)l, 16, 0, 0);
}

// ---------------------------------------------------------------------------
// fp32 -> bf16 conversion
// ---------------------------------------------------------------------------
__global__ __launch_bounds__(256) void cvt_f32_bf16(
    const float* __restrict__ src, ushort_t* __restrict__ dst, int n4)
{
    int i = blockIdx.x * 256 + threadIdx.x;
    if (i < n4) {
        float4 v = ((const float4*)src)[i];
        ushort4 o;
        o.x = f2bf(v.x); o.y = f2bf(v.y); o.z = f2bf(v.z); o.w = f2bf(v.w);
        ((ushort4*)dst)[i] = o;
    }
}

// ---------------------------------------------------------------------------
// 256x256 8-phase GEMM core (T2 swizzle + T3/T4 counted vmcnt + T5 setprio).
// A [M,768] bf16 row-major, B [N,768] bf16 row-major (output = A·B^T).
// 512 threads = 8 waves (2M x 4N); per-wave output 128x64; BK=64, 12 K-tiles,
// 2 K-tiles per iteration (slot0/slot1), 8 phases/iter.
//
// LDS swizzle: granule g of row r holds global granule g ^ (r&7)  -> the
// ds_read_b128 of 16 consecutive rows touches 8 distinct 16B granules
// (2-way = free).  global_load_lds dest is linear (wave base + lane*16);
// the source address carries the inverse swizzle (rule #21).
//
// Quarter lifetimes (read phases):  As q0,q2 read at H=0 phase; q1,q3 at H=1
// (wm selects q0-vs-q2 / q1-vs-q3).  Bs all quarters read at p0(NH=0) and
// p1(NH=1) (wn selects the quarter).  Staging always targets dead quarters:
//   p0: read A-lo+B-lo(s0); stage tb+1 A q1,q3      MFMA q(0,0)
//   p1: read B-hi(s0);      stage tb+1 B q0,q1      MFMA q(0,1)
//   p2: read A-hi(s0);      stage tb+1 B q2,q3      MFMA q(1,0)
//   p3:                     stage tb+2 A q0,q2      MFMA q(1,1)  vmcnt(2)
//   p4..p7: same on slot1, staging tb+2/tb+3.
// vmcnt(2) at p3/p7 (before the barrier) forces everything except the 2
// just-issued loads to have landed; the following barrier makes that a
// workgroup-wide guarantee.  Tail tiles clamp to 11 (idempotent restage of
// L2-hot data into dead regions; never read as new).  vmcnt(0) at core end.
// ---------------------------------------------------------------------------

template<int H>
__device__ __forceinline__ void lda_half(const ushort_t* src,
    int wm, int li, int quad, int rx, bf16x8 (&aR)[2][4])
{
#pragma unroll
    for (int kk = 0; kk < 2; ++kk)
#pragma unroll
        for (int mi = 0; mi < 4; ++mi)
            aR[kk][mi] = *(const bf16x8*)&src[
                (wm*128 + H*64 + mi*16 + li)*64 + (((kk*4+quad)^rx)*8)];
}

template<int NH>
__device__ __forceinline__ void ldb_half(const ushort_t* src,
    int wn, int li, int quad, int rx, bf16x8 (&bR)[2][2][2])
{
#pragma unroll
    for (int kk = 0; kk < 2; ++kk)
#pragma unroll
        for (int ni = 0; ni < 2; ++ni)
            bR[NH][kk][ni] = *(const bf16x8*)&src[
                (wn*64 + NH*32 + ni*16 + li)*64 + (((kk*4+quad)^rx)*8)];
}

template<int MH, int NH>
__device__ __forceinline__ void mm_q(const bf16x8 (&aR)[2][4],
    const bf16x8 (&bR)[2][2][2], floatx4 (&acc)[8][4])
{
#pragma unroll
    for (int mi = 0; mi < 4; ++mi)
#pragma unroll
        for (int ni = 0; ni < 2; ++ni)
#pragma unroll
            for (int kk = 0; kk < 2; ++kk)
                acc[MH*4+mi][NH*2+ni] = __builtin_amdgcn_mfma_f32_16x16x32_bf16(
                    aR[kk][mi], bR[NH][kk][ni], acc[MH*4+mi][NH*2+ni], 0, 0, 0);
}

// verified m201 idiom: builtin barrier + asm waitcnt + sched_barrier fence
#define BARM()  __builtin_amdgcn_s_barrier()
#define LGK0()  do { asm volatile("s_waitcnt lgkmcnt(0)" ::: "memory"); \
                     __builtin_amdgcn_sched_barrier(0); } while (0)
#define VMW2()  asm volatile("s_waitcnt vmcnt(2)" ::: "memory")
#define VMW0()  asm volatile("s_waitcnt vmcnt(0)" ::: "memory")

__device__ __forceinline__ void gemm256_core(
    const ushort_t* __restrict__ Ag, const ushort_t* __restrict__ Bg,
    const int m0, const int o0, const int maxArow, floatx4 (&acc)[8][4])
{
    __shared__ ushort_t lds[65536];   // 128 KiB: A[2][256][64] + B[2][256][64]
    const int t = threadIdx.x;
    const int w = t >> 6, lane = t & 63;
    const int quad = lane >> 4, li = lane & 15;
    const int wm = w >> 2, wn = w & 3;
    const int rx = li & 7;
    const int r8 = lane >> 3;          // row within 8-row DMA chunk
    const int g8 = (lane & 7) ^ r8;    // swizzled source granule
    const int ldw = w * 512;           // wave's linear LDS chunk (ushorts)

    ushort_t* const As0 = lds;
    ushort_t* const As1 = lds + 16384;
    ushort_t* const Bs0 = lds + 32768;
    ushort_t* const Bs1 = lds + 49152;

#pragma unroll
    for (int i = 0; i < 8; ++i)
#pragma unroll
        for (int j = 0; j < 4; ++j) acc[i][j] = (floatx4)0.f;

    // per-quarter source row bases (granule swizzle + M clamp folded in)
    const ushort_t* aB[4]; const ushort_t* bB[4];
#pragma unroll
    for (int qa = 0; qa < 4; ++qa) {
        int ra = m0 + qa*64 + w*8 + r8; if (ra > maxArow) ra = maxArow;
        aB[qa] = Ag + (size_t)ra * 768 + g8*8;
        bB[qa] = Bg + (size_t)(o0 + qa*64 + w*8 + r8) * 768 + g8*8;
    }

#define STG(base_, kt_, dst_, qa_) \
    gload_lds16((base_)[qa_] + (kt_)*64, (dst_) + (qa_)*4096 + ldw)

    // prologue: tile0 full + tile1 A q0,q2 ; then all but newest 2 landed
    STG(aB, 0, As0, 0); STG(aB, 0, As0, 1); STG(aB, 0, As0, 2); STG(aB, 0, As0, 3);
    STG(bB, 0, Bs0, 0); STG(bB, 0, Bs0, 1); STG(bB, 0, Bs0, 2); STG(bB, 0, Bs0, 3);
    STG(aB, 1, As1, 0); STG(aB, 1, As1, 2);
    VMW2(); BARM();

    bf16x8 aR[2][4];      // current A-half   [kk][mi]
    bf16x8 bR[2][2][2];   // both B-halves    [nh][kk][ni]

#pragma unroll 1
    for (int it = 0; it < 6; ++it) {
        const int tb  = 2 * it;
        const int kt1 = tb + 1;
        const int kt2 = (tb + 2 < 12) ? tb + 2 : 11;
        const int kt3 = (tb + 3 < 12) ? tb + 3 : 11;
        // ---- p0
        lda_half<0>(As0, wm, li, quad, rx, aR);
        ldb_half<0>(Bs0, wn, li, quad, rx, bR);
        STG(aB, kt1, As1, 1); STG(aB, kt1, As1, 3);
        BARM(); LGK0();
        __builtin_amdgcn_s_setprio(1); mm_q<0,0>(aR, bR, acc); __builtin_amdgcn_s_setprio(0);
        BARM();
        // ---- p1
        ldb_half<1>(Bs0, wn, li, quad, rx, bR);
        STG(bB, kt1, Bs1, 0); STG(bB, kt1, Bs1, 1);
        BARM(); LGK0();
        __builtin_amdgcn_s_setprio(1); mm_q<0,1>(aR, bR, acc); __builtin_amdgcn_s_setprio(0);
        BARM();
        // ---- p2
        lda_half<1>(As0, wm, li, quad, rx, aR);
        STG(bB, kt1, Bs1, 2); STG(bB, kt1, Bs1, 3);
        BARM(); LGK0();
        __builtin_amdgcn_s_setprio(1); mm_q<1,0>(aR, bR, acc); __builtin_amdgcn_s_setprio(0);
        BARM();
        // ---- p3
        STG(aB, kt2, As0, 0); STG(aB, kt2, As0, 2);
        BARM(); LGK0();
        __builtin_amdgcn_s_setprio(1); mm_q<1,1>(aR, bR, acc); __builtin_amdgcn_s_setprio(0);
        VMW2();
        BARM();
        // ---- p4
        lda_half<0>(As1, wm, li, quad, rx, aR);
        ldb_half<0>(Bs1, wn, li, quad, rx, bR);
        STG(aB, kt2, As0, 1); STG(aB, kt2, As0, 3);
        BARM(); LGK0();
        __builtin_amdgcn_s_setprio(1); mm_q<0,0>(aR, bR, acc); __builtin_amdgcn_s_setprio(0);
        BARM();
        // ---- p5
        ldb_half<1>(Bs1, wn, li, quad, rx, bR);
        STG(bB, kt2, Bs0, 0); STG(bB, kt2, Bs0, 1);
        BARM(); LGK0();
        __builtin_amdgcn_s_setprio(1); mm_q<0,1>(aR, bR, acc); __builtin_amdgcn_s_setprio(0);
        BARM();
        // ---- p6
        lda_half<1>(As1, wm, li, quad, rx, aR);
        STG(bB, kt2, Bs0, 2); STG(bB, kt2, Bs0, 3);
        BARM(); LGK0();
        __builtin_amdgcn_s_setprio(1); mm_q<1,0>(aR, bR, acc); __builtin_amdgcn_s_setprio(0);
        BARM();
        // ---- p7
        STG(aB, kt3, As1, 0); STG(aB, kt3, As1, 2);
        BARM(); LGK0();
        __builtin_amdgcn_s_setprio(1); mm_q<1,1>(aR, bR, acc); __builtin_amdgcn_s_setprio(0);
        VMW2();
        BARM();
    }
    VMW0();   // drain DMA before LDS dealloc at wg end
#undef STG
}

// ---------------------------------------------------------------------------
// Kernel 1: QKV projection GEMM.  Epilogue writes bf16 Q(scaled)/K/V (B,H,N,D).
// grid (9, 50): blockIdx.x = 256-col tile (3 per q/k/v group), .y = 256-row.
// ---------------------------------------------------------------------------
__global__ __launch_bounds__(512, 2) void qkv_gemm_mfma(
    const ushort_t* __restrict__ xb,   // [BN_PAD, 768] bf16
    const ushort_t* __restrict__ wb,   // [2304, 768] bf16
    const float* __restrict__ qb,
    const float* __restrict__ kb,
    const float* __restrict__ vb,
    ushort_t* __restrict__ qkvb)       // 3 x [B,H,N,D] bf16
{
    const int o0 = blockIdx.x * 256, m0 = blockIdx.y * 256;
    floatx4 acc[8][4];
    gemm256_core(xb, wb, m0, o0, BN_PAD - 1, acc);

    const int t = threadIdx.x;
    const int w = t >> 6, lane = t & 63;
    const int quad = lane >> 4, li = lane & 15;
    const int wm = w >> 2, wn = w & 3;

    const int which = blockIdx.x / 3;           // 0=q 1=k 2=v (256 | 768)
    const float* bias = (which == 0) ? qb : ((which == 1) ? kb : vb);
    ushort_t* dst = qkvb + (size_t)which * QKV_ELEMS;
    const float sc = (which == 0) ? SCALE : 1.0f;

#pragma unroll
    for (int mi = 0; mi < 8; ++mi) {
#pragma unroll
        for (int r = 0; r < 4; ++r) {
            const int m = m0 + wm * 128 + mi * 16 + quad * 4 + r;
            if (m < BN) {
                const int b = m / 197, n = m % 197;
#pragma unroll
                for (int ni = 0; ni < 4; ++ni) {
                    const int o  = o0 + wn * 64 + ni * 16 + li;
                    const int ol = o - which * 768;
                    const int h = ol >> 6, d = ol & 63;
                    dst[(((size_t)b * 12 + h) * 197 + n) * 64 + d] =
                        f2bf((acc[mi][ni][r] + bias[ol]) * sc);
                }
            }
        }
    }
}

// ---------------------------------------------------------------------------
// Kernel 2: fused MFMA attention (unchanged — verified at ~80 us).
// ---------------------------------------------------------------------------
__global__ __launch_bounds__(256, 4) void attn_mfma(
    const ushort_t* __restrict__ qkvb,    // Qb,Kb,Vb consecutive, bf16
    const float* __restrict__ rel_table,  // [732, 12]
    ushort_t* __restrict__ aout)          // [BN, 768] bf16
{
    __shared__ ushort_t Qs[64 * 64];
    __shared__ ushort_t Ks[64 * 64];
    __shared__ ushort_t Vt[64 * STRV];
    __shared__ ushort_t Ps[64 * STRV];
    __shared__ float relh[732];

    const int rt = blockIdx.x, bh = blockIdx.y;
    const int h = bh % 12, bb = bh / 12;
    const int t = threadIdx.x;
    const int w = t >> 6, lane = t & 63, quad = lane >> 4, li = lane & 15;
    const size_t base = (size_t)bh * (197 * 64);
    const ushort_t* Qg = qkvb + base;
    const ushort_t* Kg = qkvb + (size_t)QKV_ELEMS + base;
    const ushort_t* Vg = qkvb + (size_t)2 * QKV_ELEMS + base;
    const int r0 = rt * 64;

    for (int i = t; i < 732; i += 256) relh[i] = rel_table[i * 12 + h];

    {
        const int rloc = lane >> 3, g = (lane & 7) ^ rloc;
#pragma unroll
        for (int s = 0; s < 2; ++s) {
            const int rb = (w * 2 + s) * 8;
            gload_lds16(Qg + (size_t)(r0 + rb + rloc) * 64 + g * 8, &Qs[rb * 64]);
        }
    }

    int nrow[4], p14[4], pm[4];
#pragma unroll
    for (int r = 0; r < 4; ++r) {
        const int n = r0 + w * 16 + quad * 4 + r;
        nrow[r] = n;
        const int ne = (n < 197) ? n : 0;
        const int p = (ne > 0) ? ne - 1 : 0;
        p14[r] = p / 14; pm[r] = p % 14;
    }

    float m_run[4], l_run[4];
    floatx4 accO[4];
#pragma unroll
    for (int r = 0; r < 4; ++r) { m_run[r] = -INFINITY; l_run[r] = 0.f; }
#pragma unroll
    for (int dt = 0; dt < 4; ++dt) accO[dt] = (floatx4)0.f;

    __syncthreads();

    bf16x8 aq0, aq1;
    {
        const int rq = w * 16 + li, rxq = rq & 7;
        aq0 = *(const bf16x8*)&Qs[rq * 64 + (quad ^ rxq) * 8];
        aq1 = *(const bf16x8*)&Qs[rq * 64 + ((4 + quad) ^ rxq) * 8];
    }

    for (int cc = 0; cc < 4; ++cc) {
        {
            const int rloc = lane >> 3, g = (lane & 7) ^ rloc;
#pragma unroll
            for (int s = 0; s < 2; ++s) {
                const int rb = (w * 2 + s) * 8;
                gload_lds16(Kg + (size_t)(cc * 64 + rb + rloc) * 64 + g * 8,
                            &Ks[rb * 64]);
            }
        }
        {
            const int c = lane;
            const int mg = cc * 64 + c;
            ushort8 v0, v1;
            if (mg < 197) {
                v0 = *(const ushort8*)(Vg + (size_t)mg * 64 + w * 16);
                v1 = *(const ushort8*)(Vg + (size_t)mg * 64 + w * 16 + 8);
            } else {
                v0 = (ushort8)(unsigned short)0; v1 = v0;
            }
#pragma unroll
            for (int j = 0; j < 8; ++j) Vt[(w * 16 + j) * STRV + c] = v0[j];
#pragma unroll
            for (int j = 0; j < 8; ++j) Vt[(w * 16 + 8 + j) * STRV + c] = v1[j];
        }
        __syncthreads();

        floatx4 sacc[4];
#pragma unroll
        for (int tl = 0; tl < 4; ++tl) {
            const int rk = tl * 16 + li, rxk = rk & 7;
            bf16x8 bk0 = *(const bf16x8*)&Ks[rk * 64 + (quad ^ rxk) * 8];
            bf16x8 bk1 = *(const bf16x8*)&Ks[rk * 64 + ((4 + quad) ^ rxk) * 8];
            floatx4 sa = (floatx4)0.f;
            sa = __builtin_amdgcn_mfma_f32_16x16x32_bf16(aq0, bk0, sa, 0, 0, 0);
            sa = __builtin_amdgcn_mfma_f32_16x16x32_bf16(aq1, bk1, sa, 0, 0, 0);
            sacc[tl] = sa;
        }

#pragma unroll
        for (int tl = 0; tl < 4; ++tl) {
            const int mg = cc * 64 + tl * 16 + li;
            if (mg >= 197) {
#pragma unroll
                for (int r = 0; r < 4; ++r) sacc[tl][r] = -INFINITY;
            } else {
                const int qq = (mg > 0) ? mg - 1 : 0;
                const int q14 = qq / 14, qm = qq % 14;
#pragma unroll
                for (int r = 0; r < 4; ++r) {
                    int idx;
                    const int n0 = (nrow[r] < 197) ? nrow[r] : 0;
                    if (n0 == 0 && mg == 0)      idx = 731;
                    else if (n0 == 0)            idx = 729;
                    else if (mg == 0)            idx = 730;
                    else idx = (p14[r] - q14 + 13) * 27 + (pm[r] - qm + 13);
                    sacc[tl][r] += relh[idx];
                }
            }
        }

#pragma unroll
        for (int r = 0; r < 4; ++r) {
            float mx = fmaxf(fmaxf(sacc[0][r], sacc[1][r]),
                             fmaxf(sacc[2][r], sacc[3][r]));
            mx = fmaxf(mx, __shfl_xor(mx, 1));
            mx = fmaxf(mx, __shfl_xor(mx, 2));
            mx = fmaxf(mx, __shfl_xor(mx, 4));
            mx = fmaxf(mx, __shfl_xor(mx, 8));
            const float mnew = fmaxf(m_run[r], mx);
            const float alpha = __expf(m_run[r] - mnew);
            m_run[r] = mnew;
            const float p0 = __expf(sacc[0][r] - mnew);
            const float p1 = __expf(sacc[1][r] - mnew);
            const float p2 = __expf(sacc[2][r] - mnew);
            const float p3 = __expf(sacc[3][r] - mnew);
            float rs = p0 + p1 + p2 + p3;
            rs += __shfl_xor(rs, 1);
            rs += __shfl_xor(rs, 2);
            rs += __shfl_xor(rs, 4);
            rs += __shfl_xor(rs, 8);
            l_run[r] = l_run[r] * alpha + rs;
#pragma unroll
            for (int dt = 0; dt < 4; ++dt) accO[dt][r] *= alpha;
            const int prow = w * 16 + quad * 4 + r;
            Ps[prow * STRV +  0 + li] = f2bf(p0);
            Ps[prow * STRV + 16 + li] = f2bf(p1);
            Ps[prow * STRV + 32 + li] = f2bf(p2);
            Ps[prow * STRV + 48 + li] = f2bf(p3);
        }

        {
            const int rp = w * 16 + li;
            bf16x8 pa0 = *(const bf16x8*)&Ps[rp * STRV + 0  + quad * 8];
            bf16x8 pa1 = *(const bf16x8*)&Ps[rp * STRV + 32 + quad * 8];
#pragma unroll
            for (int dt = 0; dt < 4; ++dt) {
                const int rv = dt * 16 + li;
                bf16x8 bv0 = *(const bf16x8*)&Vt[rv * STRV + 0  + quad * 8];
                bf16x8 bv1 = *(const bf16x8*)&Vt[rv * STRV + 32 + quad * 8];
                accO[dt] = __builtin_amdgcn_mfma_f32_16x16x32_bf16(
                    pa0, bv0, accO[dt], 0, 0, 0);
                accO[dt] = __builtin_amdgcn_mfma_f32_16x16x32_bf16(
                    pa1, bv1, accO[dt], 0, 0, 0);
            }
        }
        __syncthreads();
    }

#pragma unroll
    for (int r = 0; r < 4; ++r) {
        const int n = nrow[r];
        if (n < 197) {
            const float inv = 1.0f / l_run[r];
            ushort_t* op = aout + ((size_t)(bb * 197 + n)) * 768 + h * 64;
#pragma unroll
            for (int dt = 0; dt < 4; ++dt)
                op[dt * 16 + li] = f2bf(accO[dt][r] * inv);
        }
    }
}

// ---------------------------------------------------------------------------
// Kernel 3: output projection GEMM (same 256^2 8-phase core), fp32 out + bias.
// grid (3, 50).
// ---------------------------------------------------------------------------
__global__ __launch_bounds__(512, 2) void proj_gemm_mfma(
    const ushort_t* __restrict__ ab,   // [BN_PAD, 768] bf16
    const ushort_t* __restrict__ wb,   // [768, 768] bf16
    const float* __restrict__ bias,    // [768]
    float* __restrict__ out)           // [BN, 768] fp32
{
    const int o0 = blockIdx.x * 256, m0 = blockIdx.y * 256;
    floatx4 acc[8][4];
    gemm256_core(ab, wb, m0, o0, BN_PAD - 1, acc);

    const int t = threadIdx.x;
    const int w = t >> 6, lane = t & 63;
    const int quad = lane >> 4, li = lane & 15;
    const int wm = w >> 2, wn = w & 3;

#pragma unroll
    for (int mi = 0; mi < 8; ++mi) {
#pragma unroll
        for (int r = 0; r < 4; ++r) {
            const int m = m0 + wm * 128 + mi * 16 + quad * 4 + r;
            if (m < BN) {
                float* op = out + (size_t)m * 768;
#pragma unroll
                for (int ni = 0; ni < 4; ++ni) {
                    const int o = o0 + wn * 64 + ni * 16 + li;
                    op[o] = acc[mi][ni][r] + bias[o];
                }
            }
        }
    }
}

// ---------------------------------------------------------------------------
// ws layout (bytes):
//   [0, 58097664)            qkvb bf16 (3 x B,H,N,D)
//   [58097664, 77561856)     xb bf16 [12672 x 768]; aliased by aout bf16
//   [77561856, 81100800)     wb bf16 [2304 x 768]
//   [81100800, 82280448)     pwb bf16 [768 x 768]
// ---------------------------------------------------------------------------
extern "C" void kernel_launch(void* const* d_in, const int* in_sizes, int n_in,
                              void* d_out, int out_size, void* d_ws, size_t ws_size,
                              hipStream_t stream)
{
    const float* x         = (const float*)d_in[0];
    const float* qkv_w     = (const float*)d_in[1];
    const float* q_bias    = (const float*)d_in[2];
    const float* k_bias    = (const float*)d_in[3];
    const float* v_bias    = (const float*)d_in[4];
    const float* rel_table = (const float*)d_in[5];
    const float* proj_w    = (const float*)d_in[6];
    const float* proj_b    = (const float*)d_in[7];
    float* out = (float*)d_out;

    char* ws = (char*)d_ws;
    ushort_t* qkvb  = (ushort_t*)ws;
    ushort_t* xb    = (ushort_t*)(ws + 58097664);
    ushort_t* aoutb = xb;                      // alias (xb dead after qkv_gemm)
    ushort_t* wb    = (ushort_t*)(ws + 77561856);
    ushort_t* pwb   = (ushort_t*)(ws + 81100800);

    cvt_f32_bf16<<<(2420736 + 255) / 256, 256, 0, stream>>>(x, xb, 2420736);
    cvt_f32_bf16<<<(442368 + 255) / 256, 256, 0, stream>>>(qkv_w, wb, 442368);
    cvt_f32_bf16<<<(147456 + 255) / 256, 256, 0, stream>>>(proj_w, pwb, 147456);

    dim3 g1(9, 50);
    qkv_gemm_mfma<<<g1, 512, 0, stream>>>(xb, wb, q_bias, k_bias, v_bias, qkvb);

    dim3 g2(4, 768);
    attn_mfma<<<g2, 256, 0, stream>>>(qkvb, rel_table, aoutb);

    dim3 g3(3, 50);
    proj_gemm_mfma<<<g3, 512, 0, stream>>>(aoutb, pwb, proj_b, out);
}

// Round 4
// 234.899 us; speedup vs baseline: 1.0782x; 1.0589x over previous
//
#include <hip/hip_runtime.h>
#include <math.h>

#define B_   64
#define N_   197
#define C_   768
#define H_   12
#define D_   64
#define BN   12608      // B_*N_
#define BN_PAD 12672    // 99*128 (GEMM M padded)
#define QKV_ELEMS 9682944   // B_*H_*N_*D_ = BN*C_
#define SCALE 0.125f    // D^-0.5
#define STRV 80         // Vt/Ps LDS row stride (ushorts): 160B, 16B-aligned

typedef unsigned short ushort_t;
using bf16x8  = __attribute__((ext_vector_type(8))) __bf16;
using floatx4 = __attribute__((ext_vector_type(4))) float;
using ushort8 = __attribute__((ext_vector_type(8))) unsigned short;

__device__ __forceinline__ ushort_t f2bf(float f) {
    union { float f; unsigned u; } v; v.f = f;
    unsigned r = v.u + 0x7FFF + ((v.u >> 16) & 1);   // RNE
    return (ushort_t)(r >> 16);
}

__device__ __forceinline__ void gload_lds16(const void* g, void* l) {
    __builtin_amdgcn_global_load_lds(
        (const __attribute__((address_space(1))) unsigned*)g,
        (__attribute__((address_space(3))) unsigned*)l, 16, 0, 0);
}

// T1: bijective XCD-chunked block remap (m204).  HW round-robins workgroup id
// across 8 XCDs (orig%8 = xcd); remap so each XCD owns a CONTIGUOUS chunk of
// tiles -> blocks sharing an A-panel / B-panel colocate on one private L2.
__device__ __forceinline__ int xcd_chunk(int orig, int nwg) {
    const int q = nwg >> 3, r = nwg & 7;
    const int x = orig & 7, i = orig >> 3;
    const int base = (x < r) ? x * (q + 1) : r * (q + 1) + (x - r) * q;
    return base + i;
}

// ---------------------------------------------------------------------------
// fused fp32 -> bf16 conversion for all three tensors (one launch)
// ranges (float4 units): x 2420736 | qkv_w 442368 | proj_w 147456
// total 3010560 = 11760 * 256 exactly.
// ---------------------------------------------------------------------------
__global__ __launch_bounds__(256) void cvt_all(
    const float* __restrict__ x,  const float* __restrict__ w1,
    const float* __restrict__ w2,
    ushort_t* __restrict__ xb, ushort_t* __restrict__ wb,
    ushort_t* __restrict__ pwb)
{
    const int i = blockIdx.x * 256 + threadIdx.x;
    const float* s; ushort_t* d; int j;
    if (i < 2420736)      { s = x;  d = xb;  j = i; }
    else if (i < 2863104) { s = w1; d = wb;  j = i - 2420736; }
    else                  { s = w2; d = pwb; j = i - 2863104; }
    float4 v = ((const float4*)s)[j];
    ushort4 o;
    o.x = f2bf(v.x); o.y = f2bf(v.y); o.z = f2bf(v.z); o.w = f2bf(v.w);
    ((ushort4*)d)[j] = o;
}

// ---------------------------------------------------------------------------
// Kernel 1: QKV projection GEMM, bf16 MFMA, BK=64, 128x128 tile, 4 waves each
// 64x64 (proven R0 core, 65.8us).  8-granule XOR swizzle: DMA lane (rloc=
// lane>>3, gl=lane&7) fetches global granule gl^rloc, so LDS granule g of row
// r holds global granule g^(r&7); frag reads un-swizzle with ^(li&7).
// Delta vs R0: XCD-chunked block swizzle only (core untouched).
// Epilogue writes bf16 Q(scaled)/K/V in (B,H,N,D).
// ---------------------------------------------------------------------------
__global__ __launch_bounds__(256, 4) void qkv_gemm_mfma(
    const ushort_t* __restrict__ xb,   // [BN_PAD, 768] bf16
    const ushort_t* __restrict__ wb,   // [2304, 768] bf16
    const float* __restrict__ qb,
    const float* __restrict__ kb,
    const float* __restrict__ vb,
    ushort_t* __restrict__ qkvb)       // 3 x [B,H,N,D] bf16
{
    __shared__ ushort_t lA[128 * 64];
    __shared__ ushort_t lB[128 * 64];
    const int t = threadIdx.x;
    const int w = t >> 6, lane = t & 63;
    const int quad = lane >> 4, li = lane & 15;
    const int wm = w >> 1, wn = w & 1;
    // XCD-chunked remap: nwg = 18*99 = 1782; chunk ~= 12.4 y-rows x 18 x-cols
    // per XCD -> B (3.5MB) + A-panel (~200KB) ~ L2-resident per XCD.
    const int f = xcd_chunk(blockIdx.y * 18 + blockIdx.x, 18 * 99);
    const int o0 = (f % 18) * 128, m0 = (f / 18) * 128;

    floatx4 acc[4][4];
#pragma unroll
    for (int i = 0; i < 4; ++i)
#pragma unroll
        for (int j = 0; j < 4; ++j) acc[i][j] = (floatx4)0.f;

    const int rloc = lane >> 3;            // row within 8-row DMA chunk
    const int gdma = (lane & 7) ^ rloc;    // swizzled global granule
    const int rx   = li & 7;               // frag-read un-swizzle key

    for (int kt = 0; kt < 12; ++kt) {
        const int k0 = kt * 64;
#pragma unroll
        for (int s = 0; s < 4; ++s) {
            const int rb = w * 32 + s * 8;
            gload_lds16(xb + ((size_t)(m0 + rb + rloc)) * 768 + k0 + gdma * 8,
                        &lA[rb * 64]);
            gload_lds16(wb + ((size_t)(o0 + rb + rloc)) * 768 + k0 + gdma * 8,
                        &lB[rb * 64]);
        }
        __syncthreads();
#pragma unroll
        for (int kk = 0; kk < 2; ++kk) {
            bf16x8 af[4], bfr[4];
#pragma unroll
            for (int mi = 0; mi < 4; ++mi)
                af[mi] = *(const bf16x8*)
                    &lA[(wm * 64 + mi * 16 + li) * 64 + ((kk * 4 + quad) ^ rx) * 8];
#pragma unroll
            for (int ni = 0; ni < 4; ++ni)
                bfr[ni] = *(const bf16x8*)
                    &lB[(wn * 64 + ni * 16 + li) * 64 + ((kk * 4 + quad) ^ rx) * 8];
#pragma unroll
            for (int mi = 0; mi < 4; ++mi)
#pragma unroll
                for (int ni = 0; ni < 4; ++ni)
                    acc[mi][ni] = __builtin_amdgcn_mfma_f32_16x16x32_bf16(
                        af[mi], bfr[ni], acc[mi][ni], 0, 0, 0);
        }
        __syncthreads();
    }

    const int which = o0 / 768;
    const float* bias = (which == 0) ? qb : ((which == 1) ? kb : vb);
    ushort_t* dst = qkvb + (size_t)which * QKV_ELEMS;
    const float sc = (which == 0) ? SCALE : 1.0f;

#pragma unroll
    for (int mi = 0; mi < 4; ++mi) {
#pragma unroll
        for (int r = 0; r < 4; ++r) {
            const int m = m0 + wm * 64 + mi * 16 + quad * 4 + r;
            if (m < BN) {
                const int b = m / 197, n = m % 197;
#pragma unroll
                for (int ni = 0; ni < 4; ++ni) {
                    const int o  = o0 + wn * 64 + ni * 16 + li;
                    const int ol = o - which * 768;
                    const int h = ol >> 6, d = ol & 63;
                    dst[(((size_t)b * 12 + h) * 197 + n) * 64 + d] =
                        f2bf((acc[mi][ni][r] + bias[ol]) * sc);
                }
            }
        }
    }
}

// ---------------------------------------------------------------------------
// Kernel 2: fused MFMA attention (core unchanged; + XCD-chunked remap so all
// 4 row-tiles of a (b,h) pair share one XCD's L2 for K/V).
// ---------------------------------------------------------------------------
__global__ __launch_bounds__(256, 4) void attn_mfma(
    const ushort_t* __restrict__ qkvb,    // Qb,Kb,Vb consecutive, bf16
    const float* __restrict__ rel_table,  // [732, 12]
    ushort_t* __restrict__ aout)          // [BN, 768] bf16
{
    __shared__ ushort_t Qs[64 * 64];
    __shared__ ushort_t Ks[64 * 64];
    __shared__ ushort_t Vt[64 * STRV];
    __shared__ ushort_t Ps[64 * STRV];
    __shared__ float relh[732];

    const int f = xcd_chunk(blockIdx.y * 4 + blockIdx.x, 4 * 768);
    const int rt = f & 3, bh = f >> 2;
    const int h = bh % 12, bb = bh / 12;
    const int t = threadIdx.x;
    const int w = t >> 6, lane = t & 63, quad = lane >> 4, li = lane & 15;
    const size_t base = (size_t)bh * (197 * 64);
    const ushort_t* Qg = qkvb + base;
    const ushort_t* Kg = qkvb + (size_t)QKV_ELEMS + base;
    const ushort_t* Vg = qkvb + (size_t)2 * QKV_ELEMS + base;
    const int r0 = rt * 64;

    for (int i = t; i < 732; i += 256) relh[i] = rel_table[i * 12 + h];

    {
        const int rloc = lane >> 3, g = (lane & 7) ^ rloc;
#pragma unroll
        for (int s = 0; s < 2; ++s) {
            const int rb = (w * 2 + s) * 8;
            gload_lds16(Qg + (size_t)(r0 + rb + rloc) * 64 + g * 8, &Qs[rb * 64]);
        }
    }

    int nrow[4], p14[4], pm[4];
#pragma unroll
    for (int r = 0; r < 4; ++r) {
        const int n = r0 + w * 16 + quad * 4 + r;
        nrow[r] = n;
        const int ne = (n < 197) ? n : 0;
        const int p = (ne > 0) ? ne - 1 : 0;
        p14[r] = p / 14; pm[r] = p % 14;
    }

    float m_run[4], l_run[4];
    floatx4 accO[4];
#pragma unroll
    for (int r = 0; r < 4; ++r) { m_run[r] = -INFINITY; l_run[r] = 0.f; }
#pragma unroll
    for (int dt = 0; dt < 4; ++dt) accO[dt] = (floatx4)0.f;

    __syncthreads();

    bf16x8 aq0, aq1;
    {
        const int rq = w * 16 + li, rxq = rq & 7;
        aq0 = *(const bf16x8*)&Qs[rq * 64 + (quad ^ rxq) * 8];
        aq1 = *(const bf16x8*)&Qs[rq * 64 + ((4 + quad) ^ rxq) * 8];
    }

    for (int cc = 0; cc < 4; ++cc) {
        {
            const int rloc = lane >> 3, g = (lane & 7) ^ rloc;
#pragma unroll
            for (int s = 0; s < 2; ++s) {
                const int rb = (w * 2 + s) * 8;
                gload_lds16(Kg + (size_t)(cc * 64 + rb + rloc) * 64 + g * 8,
                            &Ks[rb * 64]);
            }
        }
        {
            const int c = lane;
            const int mg = cc * 64 + c;
            ushort8 v0, v1;
            if (mg < 197) {
                v0 = *(const ushort8*)(Vg + (size_t)mg * 64 + w * 16);
                v1 = *(const ushort8*)(Vg + (size_t)mg * 64 + w * 16 + 8);
            } else {
                v0 = (ushort8)(unsigned short)0; v1 = v0;
            }
#pragma unroll
            for (int j = 0; j < 8; ++j) Vt[(w * 16 + j) * STRV + c] = v0[j];
#pragma unroll
            for (int j = 0; j < 8; ++j) Vt[(w * 16 + 8 + j) * STRV + c] = v1[j];
        }
        __syncthreads();

        floatx4 sacc[4];
#pragma unroll
        for (int tl = 0; tl < 4; ++tl) {
            const int rk = tl * 16 + li, rxk = rk & 7;
            bf16x8 bk0 = *(const bf16x8*)&Ks[rk * 64 + (quad ^ rxk) * 8];
            bf16x8 bk1 = *(const bf16x8*)&Ks[rk * 64 + ((4 + quad) ^ rxk) * 8];
            floatx4 sa = (floatx4)0.f;
            sa = __builtin_amdgcn_mfma_f32_16x16x32_bf16(aq0, bk0, sa, 0, 0, 0);
            sa = __builtin_amdgcn_mfma_f32_16x16x32_bf16(aq1, bk1, sa, 0, 0, 0);
            sacc[tl] = sa;
        }

#pragma unroll
        for (int tl = 0; tl < 4; ++tl) {
            const int mg = cc * 64 + tl * 16 + li;
            if (mg >= 197) {
#pragma unroll
                for (int r = 0; r < 4; ++r) sacc[tl][r] = -INFINITY;
            } else {
                const int qq = (mg > 0) ? mg - 1 : 0;
                const int q14 = qq / 14, qm = qq % 14;
#pragma unroll
                for (int r = 0; r < 4; ++r) {
                    int idx;
                    const int n0 = (nrow[r] < 197) ? nrow[r] : 0;
                    if (n0 == 0 && mg == 0)      idx = 731;
                    else if (n0 == 0)            idx = 729;
                    else if (mg == 0)            idx = 730;
                    else idx = (p14[r] - q14 + 13) * 27 + (pm[r] - qm + 13);
                    sacc[tl][r] += relh[idx];
                }
            }
        }

#pragma unroll
        for (int r = 0; r < 4; ++r) {
            float mx = fmaxf(fmaxf(sacc[0][r], sacc[1][r]),
                             fmaxf(sacc[2][r], sacc[3][r]));
            mx = fmaxf(mx, __shfl_xor(mx, 1));
            mx = fmaxf(mx, __shfl_xor(mx, 2));
            mx = fmaxf(mx, __shfl_xor(mx, 4));
            mx = fmaxf(mx, __shfl_xor(mx, 8));
            const float mnew = fmaxf(m_run[r], mx);
            const float alpha = __expf(m_run[r] - mnew);
            m_run[r] = mnew;
            const float p0 = __expf(sacc[0][r] - mnew);
            const float p1 = __expf(sacc[1][r] - mnew);
            const float p2 = __expf(sacc[2][r] - mnew);
            const float p3 = __expf(sacc[3][r] - mnew);
            float rs = p0 + p1 + p2 + p3;
            rs += __shfl_xor(rs, 1);
            rs += __shfl_xor(rs, 2);
            rs += __shfl_xor(rs, 4);
            rs += __shfl_xor(rs, 8);
            l_run[r] = l_run[r] * alpha + rs;
#pragma unroll
            for (int dt = 0; dt < 4; ++dt) accO[dt][r] *= alpha;
            const int prow = w * 16 + quad * 4 + r;
            Ps[prow * STRV +  0 + li] = f2bf(p0);
            Ps[prow * STRV + 16 + li] = f2bf(p1);
            Ps[prow * STRV + 32 + li] = f2bf(p2);
            Ps[prow * STRV + 48 + li] = f2bf(p3);
        }

        {
            const int rp = w * 16 + li;
            bf16x8 pa0 = *(const bf16x8*)&Ps[rp * STRV + 0  + quad * 8];
            bf16x8 pa1 = *(const bf16x8*)&Ps[rp * STRV + 32 + quad * 8];
#pragma unroll
            for (int dt = 0; dt < 4; ++dt) {
                const int rv = dt * 16 + li;
                bf16x8 bv0 = *(const bf16x8*)&Vt[rv * STRV + 0  + quad * 8];
                bf16x8 bv1 = *(const bf16x8*)&Vt[rv * STRV + 32 + quad * 8];
                accO[dt] = __builtin_amdgcn_mfma_f32_16x16x32_bf16(
                    pa0, bv0, accO[dt], 0, 0, 0);
                accO[dt] = __builtin_amdgcn_mfma_f32_16x16x32_bf16(
                    pa1, bv1, accO[dt], 0, 0, 0);
            }
        }
        __syncthreads();
    }

#pragma unroll
    for (int r = 0; r < 4; ++r) {
        const int n = nrow[r];
        if (n < 197) {
            const float inv = 1.0f / l_run[r];
            ushort_t* op = aout + ((size_t)(bb * 197 + n)) * 768 + h * 64;
#pragma unroll
            for (int dt = 0; dt < 4; ++dt)
                op[dt * 16 + li] = f2bf(accO[dt][r] * inv);
        }
    }
}

// ---------------------------------------------------------------------------
// Kernel 3: output projection GEMM (R0 128^2 core + XCD-chunked remap).
// ---------------------------------------------------------------------------
__global__ __launch_bounds__(256, 4) void proj_gemm_mfma(
    const ushort_t* __restrict__ ab,   // [BN_PAD, 768] bf16
    const ushort_t* __restrict__ wb,   // [768, 768] bf16
    const float* __restrict__ bias,    // [768]
    float* __restrict__ out)           // [BN, 768] fp32
{
    __shared__ ushort_t lA[128 * 64];
    __shared__ ushort_t lB[128 * 64];
    const int t = threadIdx.x;
    const int w = t >> 6, lane = t & 63;
    const int quad = lane >> 4, li = lane & 15;
    const int wm = w >> 1, wn = w & 1;
    const int f = xcd_chunk(blockIdx.y * 6 + blockIdx.x, 6 * 99);
    const int o0 = (f % 6) * 128, m0 = (f / 6) * 128;

    floatx4 acc[4][4];
#pragma unroll
    for (int i = 0; i < 4; ++i)
#pragma unroll
        for (int j = 0; j < 4; ++j) acc[i][j] = (floatx4)0.f;

    const int rloc = lane >> 3;
    const int gdma = (lane & 7) ^ rloc;
    const int rx   = li & 7;

    for (int kt = 0; kt < 12; ++kt) {
        const int k0 = kt * 64;
#pragma unroll
        for (int s = 0; s < 4; ++s) {
            const int rb = w * 32 + s * 8;
            gload_lds16(ab + ((size_t)(m0 + rb + rloc)) * 768 + k0 + gdma * 8,
                        &lA[rb * 64]);
            gload_lds16(wb + ((size_t)(o0 + rb + rloc)) * 768 + k0 + gdma * 8,
                        &lB[rb * 64]);
        }
        __syncthreads();
#pragma unroll
        for (int kk = 0; kk < 2; ++kk) {
            bf16x8 af[4], bfr[4];
#pragma unroll
            for (int mi = 0; mi < 4; ++mi)
                af[mi] = *(const bf16x8*)
                    &lA[(wm * 64 + mi * 16 + li) * 64 + ((kk * 4 + quad) ^ rx) * 8];
#pragma unroll
            for (int ni = 0; ni < 4; ++ni)
                bfr[ni] = *(const bf16x8*)
                    &lB[(wn * 64 + ni * 16 + li) * 64 + ((kk * 4 + quad) ^ rx) * 8];
#pragma unroll
            for (int mi = 0; mi < 4; ++mi)
#pragma unroll
                for (int ni = 0; ni < 4; ++ni)
                    acc[mi][ni] = __builtin_amdgcn_mfma_f32_16x16x32_bf16(
                        af[mi], bfr[ni], acc[mi][ni], 0, 0, 0);
        }
        __syncthreads();
    }

#pragma unroll
    for (int mi = 0; mi < 4; ++mi) {
#pragma unroll
        for (int r = 0; r < 4; ++r) {
            const int m = m0 + wm * 64 + mi * 16 + quad * 4 + r;
            if (m < BN) {
                float* op = out + (size_t)m * 768;
#pragma unroll
                for (int ni = 0; ni < 4; ++ni) {
                    const int o = o0 + wn * 64 + ni * 16 + li;
                    op[o] = acc[mi][ni][r] + bias[o];
                }
            }
        }
    }
}

// ---------------------------------------------------------------------------
// ws layout (bytes):
//   [0, 58097664)            qkvb bf16 (3 x B,H,N,D)
//   [58097664, 77561856)     xb bf16 [12672 x 768]; aliased by aout bf16
//   [77561856, 81100800)     wb bf16 [2304 x 768]
//   [81100800, 82280448)     pwb bf16 [768 x 768]
// ---------------------------------------------------------------------------
extern "C" void kernel_launch(void* const* d_in, const int* in_sizes, int n_in,
                              void* d_out, int out_size, void* d_ws, size_t ws_size,
                              hipStream_t stream)
{
    const float* x         = (const float*)d_in[0];
    const float* qkv_w     = (const float*)d_in[1];
    const float* q_bias    = (const float*)d_in[2];
    const float* k_bias    = (const float*)d_in[3];
    const float* v_bias    = (const float*)d_in[4];
    const float* rel_table = (const float*)d_in[5];
    const float* proj_w    = (const float*)d_in[6];
    const float* proj_b    = (const float*)d_in[7];
    float* out = (float*)d_out;

    char* ws = (char*)d_ws;
    ushort_t* qkvb  = (ushort_t*)ws;
    ushort_t* xb    = (ushort_t*)(ws + 58097664);
    ushort_t* aoutb = xb;                      // alias (xb dead after qkv_gemm)
    ushort_t* wb    = (ushort_t*)(ws + 77561856);
    ushort_t* pwb   = (ushort_t*)(ws + 81100800);

    // one fused conversion launch: 3010560 float4's exactly = 11760 * 256
    cvt_all<<<11760, 256, 0, stream>>>(x, qkv_w, proj_w, xb, wb, pwb);

    dim3 g1(18, 99);
    qkv_gemm_mfma<<<g1, 256, 0, stream>>>(xb, wb, q_bias, k_bias, v_bias, qkvb);

    dim3 g2(4, 768);
    attn_mfma<<<g2, 256, 0, stream>>>(qkvb, rel_table, aoutb);

    dim3 g3(6, 99);
    proj_gemm_mfma<<<g3, 256, 0, stream>>>(aoutb, pwb, proj_b, out);
}